// Round 1
// baseline (74.848 us; speedup 1.0000x reference)
//
#include <hip/hip_runtime.h>
#include <hip/hip_bf16.h>
#include <math.h>

#define BATCH 16384
#define OUTF  1024
#define INF   1024
#define KPROJ 256
#define MTOT  (BATCH + OUTF)   // 17408

#define GBM 64
#define GBN 128
#define GBK 64
#define NKT (INF / GBK)        // 16

#define NZ_THRESH 0.15f        // ~6.8 sigma of f16 dot error (sigma ~0.022)

typedef unsigned int       u32;
typedef unsigned long long u64;
typedef unsigned short     u16;
typedef _Float16           f16;
typedef __attribute__((ext_vector_type(8))) _Float16 f16x8;
typedef __attribute__((ext_vector_type(4))) float    f32x4;

#define SCHED0() __builtin_amdgcn_sched_barrier(0)

__device__ __forceinline__ void gl_lds16(const void* g, void* l) {
    __builtin_amdgcn_global_load_lds(
        (const __attribute__((address_space(1))) u32*)g,
        (__attribute__((address_space(3))) u32*)l, 16, 0, 0);
}

// ---------------------------------------------------------------------------
// prep_p: convert P (256 rows x 1024) fp32 -> f16 (RN). One wave per row.
// ---------------------------------------------------------------------------
__global__ __launch_bounds__(256) void prep_p(const float* __restrict__ P,
                                              f16* __restrict__ Bp) {
    const int wave = threadIdx.x >> 6, lane = threadIdx.x & 63;
    const int pr = blockIdx.x * 4 + wave;             // 0..255
    const float4* v = (const float4*)(P + (size_t)pr * INF);
    ushort4* d = (ushort4*)(Bp + (size_t)pr * INF);
#pragma unroll
    for (int q = 0; q < 4; ++q) {
        float4 f = v[lane + 64 * q];
        ushort4 o;
        o.x = __builtin_bit_cast(u16, (f16)f.x);
        o.y = __builtin_bit_cast(u16, (f16)f.y);
        o.z = __builtin_bit_cast(u16, (f16)f.z);
        o.w = __builtin_bit_cast(u16, (f16)f.w);
        d[lane + 64 * q] = o;
    }
}

// ---------------------------------------------------------------------------
// f16 MFMA sign GEMM, truly pipelined:
//   BM=64 x BN=128 x BK=64, 256 thr (4 waves across N, each wave 64x32).
//   ldsB double-buffered: B(k+1) issued via global_load_lds during iter k and
//   waited with counted vmcnt(8) one iteration later (loads span both
//   barriers). A is reg-prefetched at distance TWO (issued after the mid
//   wait, so the in-order vmcnt drain never pulls it in early) -> ~2 iters to
//   cover HBM latency. Single-buffer ldsA is race-free: stage(k) writes it
//   between barrier2(k-1) and barrier1(k); all reads are inside the barrier
//   pair of their own iteration.
// Steady-state vmem queue: [A_k(4), B_k(4), A_{k+1}(4)] at top of iter k.
//   top  vmcnt(8): drains A_k      (stage inputs ready)
//   mid  vmcnt(8): drains B_k      (compute tile ready; B_{k+1} stays in
//                                   flight across both barriers)
// Epilogue: fused fp64 fixup for near-zero dots + ballot sign-pack + norms.
// ---------------------------------------------------------------------------
__global__ __launch_bounds__(256, 3) void gemm_signs(const float* __restrict__ X,
                                                     const float* __restrict__ W,
                                                     const f16* __restrict__ Bp,
                                                     const float* __restrict__ Pf,
                                                     u64* __restrict__ cx,
                                                     u64* __restrict__ cw,
                                                     float* __restrict__ xn,
                                                     float* __restrict__ wn) {
    __shared__ __align__(16) unsigned char ldsA[GBM * 128];        //  8 KB
    __shared__ __align__(16) unsigned char ldsB[2 * GBN * 128];    // 32 KB (dbuf)
    __shared__ u16 sw[GBM][8];
    __shared__ float nsq[GBM][8];

    const int t    = threadIdx.x;
    const int wid  = t >> 6, lane = t & 63;
    const int l4   = lane >> 4, l15 = lane & 15;
    const int wc   = wid;                       // 4 waves across N
    const int bm   = blockIdx.x >> 1;
    const int bn0  = (blockIdx.x & 1) * GBN;
    const int am0  = bm * GBM;

    // A staging map: thread t -> chunk ca of rows ra and ra+32 (row+32 has the
    // same &7, hence the same swizzled chunk), written at linear slots t and
    // t+256 (both conflict-free contiguous b128 writes).
    const int ra = t >> 3, sa = t & 7, ca = sa ^ (ra & 7);
    const float* Asrc = (am0 < BATCH) ? X + (size_t)am0 * INF
                                      : W + (size_t)(am0 - BATCH) * INF;
    const float* aRow0 = Asrc + (size_t)ra * INF + ca * 8;
    const float* aRow1 = aRow0 + (size_t)32 * INF;

    // B staging map (global_load_lds): wave wid, rep i covers linear chunks
    const f16* bsrc[4];
#pragma unroll
    for (int i = 0; i < 4; ++i) {
        const int g = (i * 4 + wid) * 64 + lane;
        const int row = g >> 3, sl = g & 7, cb = sl ^ (row & 7);
        bsrc[i] = Bp + (size_t)(bn0 + row) * INF + cb * 8;
    }

    f32x4 acc[4][2] = {};
    float ssq0 = 0.0f, ssq1 = 0.0f;
    float4 pa0, pa1, pa2, pa3, pb0, pb1, pb2, pb3;

#define GEMM_ALOAD(P0, P1, P2, P3, KT2)                                       \
    P0 = *(const float4*)(aRow0 + (KT2) * GBK);                               \
    P1 = *(const float4*)(aRow0 + (KT2) * GBK + 4);                           \
    P2 = *(const float4*)(aRow1 + (KT2) * GBK);                               \
    P3 = *(const float4*)(aRow1 + (KT2) * GBK + 4);

#define GEMM_BISSUE(KT1, NXTOFF)                                              \
    _Pragma("unroll")                                                         \
    for (int i = 0; i < 4; ++i)                                               \
        gl_lds16(bsrc[i] + (KT1) * GBK,                                       \
                 ldsB + (NXTOFF) + (i * 4 + wid) * 1024);

#define GEMM_STAGE(P0, P1, P2, P3)                                            \
    {                                                                         \
        ssq0 += P0.x * P0.x + P0.y * P0.y + P0.z * P0.z + P0.w * P0.w +       \
                P1.x * P1.x + P1.y * P1.y + P1.z * P1.z + P1.w * P1.w;        \
        ssq1 += P2.x * P2.x + P2.y * P2.y + P2.z * P2.z + P2.w * P2.w +       \
                P3.x * P3.x + P3.y * P3.y + P3.z * P3.z + P3.w * P3.w;        \
        f16x8 h0, h1;                                                         \
        h0[0] = (f16)P0.x; h0[1] = (f16)P0.y; h0[2] = (f16)P0.z;              \
        h0[3] = (f16)P0.w; h0[4] = (f16)P1.x; h0[5] = (f16)P1.y;              \
        h0[6] = (f16)P1.z; h0[7] = (f16)P1.w;                                 \
        h1[0] = (f16)P2.x; h1[1] = (f16)P2.y; h1[2] = (f16)P2.z;              \
        h1[3] = (f16)P2.w; h1[4] = (f16)P3.x; h1[5] = (f16)P3.y;              \
        h1[6] = (f16)P3.z; h1[7] = (f16)P3.w;                                 \
        *(f16x8*)(ldsA + t * 16) = h0;                                        \
        *(f16x8*)(ldsA + 4096 + t * 16) = h1;                                 \
    }

#define GEMM_COMPUTE(BOFF)                                                    \
    _Pragma("unroll")                                                         \
    for (int ks = 0; ks < 2; ++ks) {                                          \
        f16x8 af[4], bf[2];                                                   \
        _Pragma("unroll")                                                     \
        for (int i = 0; i < 4; ++i) {                                         \
            const int row = i * 16 + l15;                                     \
            const int slot = (ks * 4 + l4) ^ (row & 7);                       \
            af[i] = *(const f16x8*)(ldsA + row * 128 + slot * 16);            \
        }                                                                     \
        _Pragma("unroll")                                                     \
        for (int j = 0; j < 2; ++j) {                                         \
            const int col = wc * 32 + j * 16 + l15;                           \
            const int slot = (ks * 4 + l4) ^ (col & 7);                       \
            bf[j] = *(const f16x8*)(ldsB + (BOFF) + col * 128 + slot * 16);   \
        }                                                                     \
        _Pragma("unroll")                                                     \
        for (int i = 0; i < 4; ++i)                                           \
            _Pragma("unroll")                                                 \
            for (int j = 0; j < 2; ++j)                                       \
                acc[i][j] = __builtin_amdgcn_mfma_f32_16x16x32_f16(           \
                    af[i], bf[j], acc[i][j], 0, 0, 0);                        \
    }

#define GEMM_BODY(P0, P1, P2, P3, KT, CUROFF, NXTOFF, DO_A, DO_B, VMTOP, VMMID) \
    {                                                                         \
        asm volatile("s_waitcnt vmcnt(" VMTOP ")" ::: "memory");              \
        SCHED0();                                                             \
        GEMM_STAGE(P0, P1, P2, P3);                                          \
        SCHED0();                                                             \
        if (DO_B) { GEMM_BISSUE((KT) + 1, NXTOFF); }                          \
        SCHED0();                                                             \
        asm volatile("s_waitcnt vmcnt(" VMMID ") lgkmcnt(0)" ::: "memory");   \
        SCHED0();                                                             \
        if (DO_A) { GEMM_ALOAD(P0, P1, P2, P3, (KT) + 2); }                   \
        SCHED0();                                                             \
        __builtin_amdgcn_s_barrier();                                         \
        SCHED0();                                                             \
        GEMM_COMPUTE(CUROFF);                                                 \
        SCHED0();                                                             \
        __builtin_amdgcn_s_barrier();                                         \
    }

    // prologue: vmem queue becomes [A0(4), B0(4), A1(4)]
    GEMM_ALOAD(pa0, pa1, pa2, pa3, 0);
    GEMM_BISSUE(0, 0);
    GEMM_ALOAD(pb0, pb1, pb2, pb3, 1);
    SCHED0();

    for (int kt = 0; kt < 14; kt += 2) {
        GEMM_BODY(pa0, pa1, pa2, pa3, kt,     0,     16384, true,  true,  "8", "8");
        GEMM_BODY(pb0, pb1, pb2, pb3, kt + 1, 16384, 0,     true,  true,  "8", "8");
    }
    // kt = 14: no A16; B15 still issued.  queue in: [A14,B14,A15]
    GEMM_BODY(pa0, pa1, pa2, pa3, 14, 0,     16384, false, true,  "8", "8");
    // kt = 15: nothing left to issue.     queue in: [A15,B15]
    GEMM_BODY(pb0, pb1, pb2, pb3, 15, 16384, 0,     false, false, "4", "0");

    nsq[ra][sa]      = ssq0;
    nsq[ra + 32][sa] = ssq1;

    // epilogue: fused fp64 fixup for near-zero dots, then ballot sign-pack.
    // C layout: local row = i*16 + l4*4 + q, col = bn0 + wc*32 + j*16 + l15.
#pragma unroll
    for (int i = 0; i < 4; ++i)
#pragma unroll
        for (int j = 0; j < 2; ++j)
#pragma unroll
            for (int q = 0; q < 4; ++q) {
                const float v = acc[i][j][q];
                int bit = (v >= 0.0f) ? 1 : 0;
                u64 fl = __ballot(fabsf(v) < NZ_THRESH);
                while (fl) {   // rare (~8/wave): whole wave re-dots in fp64
                    const int src = __ffsll((long long)fl) - 1;
                    fl &= fl - 1;
                    const int lrow = i * 16 + ((src >> 4) << 2) + q;
                    const int col  = bn0 + wc * 32 + j * 16 + (src & 15);
                    const float* xr = Asrc + (size_t)lrow * INF + lane * 16;
                    const float* pr = Pf + (size_t)col * INF + lane * 16;
                    double s = 0.0;
#pragma unroll
                    for (int c4 = 0; c4 < 4; ++c4) {
                        float4 xa = *(const float4*)(xr + c4 * 4);
                        float4 pa = *(const float4*)(pr + c4 * 4);
                        s += (double)xa.x * pa.x + (double)xa.y * pa.y +
                             (double)xa.z * pa.z + (double)xa.w * pa.w;
                    }
#pragma unroll
                    for (int off = 32; off; off >>= 1) s += __shfl_xor(s, off, 64);
                    if (lane == src) bit = (s >= 0.0) ? 1 : 0;
                }
                const u64 b = __ballot(bit != 0);
                if (l15 == 0)
                    sw[i * 16 + l4 * 4 + q][wc * 2 + j] = (u16)(b >> (l4 * 16));
            }
    __syncthreads();
    if (bn0 == 0 && t < GBM) {   // fused norm write (one block-column only)
        const float* p = nsq[t];
        float s = ((p[0] + p[1]) + (p[2] + p[3])) + ((p[4] + p[5]) + (p[6] + p[7]));
        const float n = sqrtf(s) + 1.1920929e-07f;
        const int grow = am0 + t;
        if (grow < BATCH) xn[grow] = n; else wn[grow - BATCH] = n;
    }
    if (t < 128) {
        const int r = t >> 1, wsel = t & 1;
        const u64 val = *(const u64*)&sw[r][wsel * 4];
        const int grow = am0 + r;
        const int word = (blockIdx.x & 1) * 2 + wsel;
        if (grow < BATCH) cx[(size_t)grow * 4 + word] = val;
        else              cw[(size_t)(grow - BATCH) * 4 + word] = val;
    }
}

// ---------------------------------------------------------------------------
// out[b][m] = xn[b] * wn[m] * cos(pi * popc / 256)
// ---------------------------------------------------------------------------
__global__ __launch_bounds__(256) void popc_out(const u64* __restrict__ cx,
                                                const u64* __restrict__ cw,
                                                const float* __restrict__ xn,
                                                const float* __restrict__ wn,
                                                float* __restrict__ out) {
    __shared__ float lut[257];
    __shared__ u64 cxs[64][4];
    __shared__ float xns[64];
    const int t = threadIdx.x;

    lut[t] = (float)cos((double)t * (3.14159265358979323846 / 256.0));
    if (t == 0) lut[256] = -1.0f;

    const int r0 = blockIdx.x * 64;
    cxs[t >> 2][t & 3] = cx[(size_t)r0 * 4 + t];
    if (t < 64) xns[t] = xn[r0 + t];

    const ulonglong4* cwv4 = (const ulonglong4*)cw;
    ulonglong4 c0 = cwv4[4 * t + 0];
    ulonglong4 c1 = cwv4[4 * t + 1];
    ulonglong4 c2 = cwv4[4 * t + 2];
    ulonglong4 c3 = cwv4[4 * t + 3];
    float4 wnr = ((const float4*)wn)[t];

    __syncthreads();

    float4* outv = (float4*)out;
    const size_t obase = (size_t)r0 * (OUTF / 4) + t;
#pragma unroll 4
    for (int r = 0; r < 64; ++r) {
        const u64 a0 = cxs[r][0], a1 = cxs[r][1], a2 = cxs[r][2], a3 = cxs[r][3];
        const float sx = xns[r];
        float4 o;
        o.x = sx * wnr.x * lut[__popcll(a0 ^ c0.x) + __popcll(a1 ^ c0.y) +
                               __popcll(a2 ^ c0.z) + __popcll(a3 ^ c0.w)];
        o.y = sx * wnr.y * lut[__popcll(a0 ^ c1.x) + __popcll(a1 ^ c1.y) +
                               __popcll(a2 ^ c1.z) + __popcll(a3 ^ c1.w)];
        o.z = sx * wnr.z * lut[__popcll(a0 ^ c2.x) + __popcll(a1 ^ c2.y) +
                               __popcll(a2 ^ c2.z) + __popcll(a3 ^ c2.w)];
        o.w = sx * wnr.w * lut[__popcll(a0 ^ c3.x) + __popcll(a1 ^ c3.y) +
                               __popcll(a2 ^ c3.z) + __popcll(a3 ^ c3.w)];
        outv[obase + (size_t)r * (OUTF / 4)] = o;
    }
}

extern "C" void kernel_launch(void* const* d_in, const int* in_sizes, int n_in,
                              void* d_out, int out_size, void* d_ws, size_t ws_size,
                              hipStream_t stream) {
    const float* x = (const float*)d_in[0];
    const float* w = (const float*)d_in[1];
    const float* P = (const float*)d_in[2];
    float* out = (float*)d_out;

    char* ws = (char*)d_ws;
    f16*  Bp = (f16*)ws;                         // +0        (524288 B)
    u64*  cx = (u64*)(ws + 524288);              // +524288   (524288 B)
    u64*  cw = (u64*)(ws + 1048576);             // +1048576  (32768 B)
    float* xn = (float*)(ws + 1081344);          // +1081344  (65536 B)
    float* wn = (float*)(ws + 1146880);          // +1146880  (4096 B)

    prep_p<<<KPROJ / 4, 256, 0, stream>>>(P, Bp);

    gemm_signs<<<(MTOT / GBM) * 2, 256, 0, stream>>>(x, w, Bp, P, cx, cw, xn, wn);

    popc_out<<<BATCH / 64, 256, 0, stream>>>(cx, cw, xn, wn, out);
}